// Round 7
// baseline (122.018 us; speedup 1.0000x reference)
//
#include <hip/hip_runtime.h>

// (B,C,H,W)=(32,32,64,64), D=32, K=512
#define C_    32
#define D_    32
#define K_    512
#define HW_   4096
#define NTOK  131072
#define IDX_OFF   4194304
#define LOSS_OFF  4325376
#define TAU   2e-3f
#define NBLK  4096               // NTOK/32 token-tiles

// ws: cbn @0, cbh @4096, cbl @36864, lossp @69632 (NBLK f32)
#define WS_CBN   0
#define WS_CBH   4096
#define WS_CBL   36864
#define WS_LOSSP 69632
#define WS_NEEDED (69632 + NBLK * 4)

typedef __attribute__((ext_vector_type(8))) __bf16 bf16x8;
typedef __attribute__((ext_vector_type(8))) short  short8;
typedef __attribute__((ext_vector_type(4))) float  f32x4;

__device__ inline unsigned short f2bf(float x) {          // RNE fp32->bf16
    unsigned u = __builtin_bit_cast(unsigned, x);
    return (unsigned short)((u + 0x7FFFu + ((u >> 16) & 1u)) >> 16);
}
__device__ inline float bf2f(unsigned short h) {
    unsigned u = ((unsigned)h) << 16; return __builtin_bit_cast(float, u);
}

// ---------- codebook split + norms ----------
__global__ __launch_bounds__(256)
void prep_cb(const float* __restrict__ cb, float* __restrict__ cbn,
             unsigned short* __restrict__ cbh, unsigned short* __restrict__ cbl)
{
    const int k = blockIdx.x * 256 + threadIdx.x;   // grid=2
    const float* row = cb + k * D_;
    float s = 0.f;
    unsigned short h[32], lo[32];
    #pragma unroll
    for (int d = 0; d < D_; ++d) {
        const float v = row[d]; s = fmaf(v, v, s);
        const unsigned short hh = f2bf(v);
        h[d] = hh; lo[d] = f2bf(v - bf2f(hh));
    }
    cbn[k] = s;
    #pragma unroll
    for (int j = 0; j < 4; ++j) {
        *(short8*)(cbh + k * 32 + 8 * j) = *(const short8*)(h  + 8 * j);
        *(short8*)(cbl + k * 32 + 8 * j) = *(const short8*)(lo + 8 * j);
    }
}

// ---------- fused: 32 tokens/block, 4 waves split K (128 codes each) ----------
__global__ __launch_bounds__(256, 4)
void vq_fused(const float* __restrict__ z,  const float* __restrict__ qw,
              const float* __restrict__ qb, const float* __restrict__ cb,
              const float* __restrict__ pw, const float* __restrict__ pb,
              const unsigned short* __restrict__ cbh, const unsigned short* __restrict__ cbl,
              const float* __restrict__ cbn, float* __restrict__ lossp,
              float* __restrict__ out)
{
    __shared__ float xsh[32][33];
    __shared__ float qsh[32][33];
    __shared__ float rb1[4][32], rb2[4][32];
    __shared__ int   ri[4][32];
    __shared__ int   sidx[32];
    __shared__ float lsum[4];

    const int tid = threadIdx.x;
    const int wv = tid >> 6, l = tid & 63;
    const int T0 = blockIdx.x * 32;
    const int b = T0 >> 12, hw0 = T0 & (HW_ - 1);
    const int tok = tid & 31, grp = tid >> 5;          // grp 0..7

    // ---- phase 1: quant conv — lane computes 4 d-channels of its token ----
    {
        const float* zbase = z + (size_t)b * (C_ * HW_) + hw0 + tok;
        const int d0 = grp * 4;
        float a0 = qb[d0], a1 = qb[d0 + 1], a2 = qb[d0 + 2], a3 = qb[d0 + 3];
        #pragma unroll
        for (int c4 = 0; c4 < 8; ++c4) {
            const float zc0 = zbase[(size_t)(c4 * 4 + 0) * HW_];
            const float zc1 = zbase[(size_t)(c4 * 4 + 1) * HW_];
            const float zc2 = zbase[(size_t)(c4 * 4 + 2) * HW_];
            const float zc3 = zbase[(size_t)(c4 * 4 + 3) * HW_];
            const float4 q0 = *(const float4*)(qw + (d0 + 0) * C_ + c4 * 4);
            const float4 q1 = *(const float4*)(qw + (d0 + 1) * C_ + c4 * 4);
            const float4 q2 = *(const float4*)(qw + (d0 + 2) * C_ + c4 * 4);
            const float4 q3 = *(const float4*)(qw + (d0 + 3) * C_ + c4 * 4);
            a0 = fmaf(zc0, q0.x, a0); a0 = fmaf(zc1, q0.y, a0); a0 = fmaf(zc2, q0.z, a0); a0 = fmaf(zc3, q0.w, a0);
            a1 = fmaf(zc0, q1.x, a1); a1 = fmaf(zc1, q1.y, a1); a1 = fmaf(zc2, q1.z, a1); a1 = fmaf(zc3, q1.w, a1);
            a2 = fmaf(zc0, q2.x, a2); a2 = fmaf(zc1, q2.y, a2); a2 = fmaf(zc2, q2.z, a2); a2 = fmaf(zc3, q2.w, a2);
            a3 = fmaf(zc0, q3.x, a3); a3 = fmaf(zc1, q3.y, a3); a3 = fmaf(zc2, q3.z, a3); a3 = fmaf(zc3, q3.w, a3);
        }
        xsh[tok][grp * 4 + 0] = a0; xsh[tok][grp * 4 + 1] = a1;
        xsh[tok][grp * 4 + 2] = a2; xsh[tok][grp * 4 + 3] = a3;
    }
    __syncthreads();

    // ---- A fragments (row=lane&15 token, k-chunk=(lane>>4)*8), hi/lo split ----
    const int lr = l & 15, lg = l >> 4;
    short8 sh0, sl0, sh1, sl1;
    #pragma unroll
    for (int j = 0; j < 8; ++j) {
        const float v0 = xsh[lr][lg * 8 + j];
        const float v1 = xsh[16 + lr][lg * 8 + j];
        const unsigned short h0 = f2bf(v0), h1 = f2bf(v1);
        sh0[j] = (short)h0; sl0[j] = (short)f2bf(v0 - bf2f(h0));
        sh1[j] = (short)h1; sl1[j] = (short)f2bf(v1 - bf2f(h1));
    }
    const bf16x8 ah0 = __builtin_bit_cast(bf16x8, sh0);
    const bf16x8 al0 = __builtin_bit_cast(bf16x8, sl0);
    const bf16x8 ah1 = __builtin_bit_cast(bf16x8, sh1);
    const bf16x8 al1 = __builtin_bit_cast(bf16x8, sl1);

    // ---- phase 2: this wave scans its 128-code quarter (8 iterations) ----
    const int kbase = wv * 128;
    float b1[8], b2[8]; int i1[8];
    #pragma unroll
    for (int s = 0; s < 8; ++s) { b1[s] = 3.4e38f; b2[s] = 3.4e38f; i1[s] = 0; }

    #pragma unroll 2
    for (int nt = 0; nt < 8; ++nt) {
        const int krow = kbase + nt * 16 + lr;
        const size_t boff = (size_t)krow * 32 + lg * 8;
        const bf16x8 bh = __builtin_bit_cast(bf16x8, *(const short8*)(cbh + boff));
        const bf16x8 bl = __builtin_bit_cast(bf16x8, *(const short8*)(cbl + boff));
        const float cn = cbn[krow];
        f32x4 acc0 = {0.f,0.f,0.f,0.f}, acc1 = {0.f,0.f,0.f,0.f};
        acc0 = __builtin_amdgcn_mfma_f32_16x16x32_bf16(ah0, bh, acc0, 0, 0, 0);
        acc0 = __builtin_amdgcn_mfma_f32_16x16x32_bf16(ah0, bl, acc0, 0, 0, 0);
        acc0 = __builtin_amdgcn_mfma_f32_16x16x32_bf16(al0, bh, acc0, 0, 0, 0);
        acc1 = __builtin_amdgcn_mfma_f32_16x16x32_bf16(ah1, bh, acc1, 0, 0, 0);
        acc1 = __builtin_amdgcn_mfma_f32_16x16x32_bf16(ah1, bl, acc1, 0, 0, 0);
        acc1 = __builtin_amdgcn_mfma_f32_16x16x32_bf16(al1, bh, acc1, 0, 0, 0);
        #pragma unroll
        for (int r = 0; r < 4; ++r) {
            {
                const float d2 = fmaf(-2.f, acc0[r], cn);
                const bool lt1 = d2 < b1[r], lt2 = d2 < b2[r];
                b2[r] = lt1 ? b1[r] : (lt2 ? d2 : b2[r]);
                b1[r] = lt1 ? d2 : b1[r];
                i1[r] = lt1 ? krow : i1[r];
            }
            {
                const float d2 = fmaf(-2.f, acc1[r], cn);
                const bool lt1 = d2 < b1[4+r], lt2 = d2 < b2[4+r];
                b2[4+r] = lt1 ? b1[4+r] : (lt2 ? d2 : b2[4+r]);
                b1[4+r] = lt1 ? d2 : b1[4+r];
                i1[4+r] = lt1 ? krow : i1[4+r];
            }
        }
    }
    // merge top-2 across the 16 n-lanes of each lg group
    #pragma unroll
    for (int mk = 1; mk < 16; mk <<= 1) {
        #pragma unroll
        for (int s = 0; s < 8; ++s) {
            const float ob1 = __shfl_xor(b1[s], mk);
            const int   oi1 = __shfl_xor(i1[s], mk);
            const float ob2 = __shfl_xor(b2[s], mk);
            const bool take = (ob1 < b1[s]) || (ob1 == b1[s] && oi1 < i1[s]);
            const float loser = take ? b1[s] : ob1;
            b1[s] = take ? ob1 : b1[s];
            i1[s] = take ? oi1 : i1[s];
            b2[s] = fminf(fminf(b2[s], ob2), loser);
        }
    }
    #pragma unroll
    for (int s = 0; s < 8; ++s) {
        if (lr == s) {
            const int tokW = (s >> 2) * 16 + lg * 4 + (s & 3);
            rb1[wv][tokW] = b1[s]; rb2[wv][tokW] = b2[s]; ri[wv][tokW] = i1[s];
        }
    }
    __syncthreads();

    // ---- final merge (lanes 0..31 of wave 0), wave-ascending => first-min ----
    if (tid < 32) {
        float B1 = rb1[0][tid], B2 = rb2[0][tid]; int I = ri[0][tid];
        #pragma unroll
        for (int w = 1; w < 4; ++w) {
            const float o1 = rb1[w][tid], o2 = rb2[w][tid]; const int oi = ri[w][tid];
            const bool take = o1 < B1;
            const float loser = take ? B1 : o1;
            B2 = fminf(fminf(B2, o2), loser);
            if (take) { B1 = o1; I = oi; }
        }
        sidx[tid] = I | (((B2 - B1) < TAU) ? 512 : 0);
    }
    __syncthreads();

    // ---- phase 3: exact fp32 rescan of flagged tokens (wave 0, rare) ----
    if (wv == 0) {
        const int sv = sidx[l & 31];
        unsigned long long m = __ballot((l < 32) && (sv & 512));
        while (m) {
            const int j = __ffsll(m) - 1; m &= m - 1;
            float xfj[D_];
            #pragma unroll
            for (int d = 0; d < D_; ++d) xfj[d] = xsh[j][d];
            float bb = 3.4e38f; int bi = 0;
            #pragma unroll
            for (int p = 0; p < 8; ++p) {
                const int c = l + 64 * p;
                const float* row = cb + (size_t)c * D_;
                float p0 = 0.f, p1 = 0.f, p2 = 0.f, p3 = 0.f;
                #pragma unroll
                for (int d = 0; d < D_; d += 4) {
                    p0 = fmaf(xfj[d],   row[d],   p0); p1 = fmaf(xfj[d+1], row[d+1], p1);
                    p2 = fmaf(xfj[d+2], row[d+2], p2); p3 = fmaf(xfj[d+3], row[d+3], p3);
                }
                const float dd = fmaf(-2.f, (p0 + p1) + (p2 + p3), cbn[c]);
                if (dd < bb) { bb = dd; bi = c; }
            }
            #pragma unroll
            for (int s = 1; s < 64; s <<= 1) {
                const float ob = __shfl_xor(bb, s); const int oi = __shfl_xor(bi, s);
                if (ob < bb || (ob == bb && oi < bi)) { bb = ob; bi = oi; }
            }
            if (l == j) sidx[j] = bi;
        }
    }
    __syncthreads();
    const int myidx = sidx[tok] & 511;

    // ---- phase 4: gather (lane's 4 dims), loss, idx write, post conv ----
    {
        const float4 q4 = *(const float4*)(cb + (size_t)myidx * D_ + grp * 4);
        qsh[tok][grp * 4 + 0] = q4.x; qsh[tok][grp * 4 + 1] = q4.y;
        qsh[tok][grp * 4 + 2] = q4.z; qsh[tok][grp * 4 + 3] = q4.w;
    }
    __syncthreads();

    float lacc = 0.f;
    #pragma unroll
    for (int i = 0; i < 4; ++i) {
        const float df = qsh[tok][grp * 4 + i] - xsh[tok][grp * 4 + i];
        lacc = fmaf(df, df, lacc);
    }
    lacc += __shfl_down(lacc, 32); lacc += __shfl_down(lacc, 16);
    lacc += __shfl_down(lacc, 8);  lacc += __shfl_down(lacc, 4);
    lacc += __shfl_down(lacc, 2);  lacc += __shfl_down(lacc, 1);
    if (l == 0) lsum[wv] = lacc;

    if (tid < 32) out[IDX_OFF + T0 + tid] = (float)(sidx[tid] & 511);

    // post conv: lane computes 4 out-channels c = grp*4..+3 of its token
    {
        const int c0 = grp * 4;
        float a0 = pb[c0], a1 = pb[c0 + 1], a2 = pb[c0 + 2], a3 = pb[c0 + 3];
        #pragma unroll
        for (int d4 = 0; d4 < 8; ++d4) {
            const float q0 = qsh[tok][d4 * 4 + 0];
            const float q1 = qsh[tok][d4 * 4 + 1];
            const float q2 = qsh[tok][d4 * 4 + 2];
            const float q3 = qsh[tok][d4 * 4 + 3];
            const float4 p0 = *(const float4*)(pw + (c0 + 0) * D_ + d4 * 4);
            const float4 p1 = *(const float4*)(pw + (c0 + 1) * D_ + d4 * 4);
            const float4 p2 = *(const float4*)(pw + (c0 + 2) * D_ + d4 * 4);
            const float4 p3 = *(const float4*)(pw + (c0 + 3) * D_ + d4 * 4);
            a0 = fmaf(q0, p0.x, a0); a0 = fmaf(q1, p0.y, a0); a0 = fmaf(q2, p0.z, a0); a0 = fmaf(q3, p0.w, a0);
            a1 = fmaf(q0, p1.x, a1); a1 = fmaf(q1, p1.y, a1); a1 = fmaf(q2, p1.z, a1); a1 = fmaf(q3, p1.w, a1);
            a2 = fmaf(q0, p2.x, a2); a2 = fmaf(q1, p2.y, a2); a2 = fmaf(q2, p2.z, a2); a2 = fmaf(q3, p2.w, a2);
            a3 = fmaf(q0, p3.x, a3); a3 = fmaf(q1, p3.y, a3); a3 = fmaf(q2, p3.z, a3); a3 = fmaf(q3, p3.w, a3);
        }
        float* obase = out + (size_t)b * (C_ * HW_) + hw0 + tok;
        obase[(size_t)(c0 + 0) * HW_] = a0;
        obase[(size_t)(c0 + 1) * HW_] = a1;
        obase[(size_t)(c0 + 2) * HW_] = a2;
        obase[(size_t)(c0 + 3) * HW_] = a3;
    }

    __syncthreads();
    if (tid == 0)
        lossp[blockIdx.x] = (lsum[0] + lsum[1]) + (lsum[2] + lsum[3]);
}

// ---------- loss finalize (single block) ----------
__global__ __launch_bounds__(256)
void loss_final(const float* __restrict__ lossp, float* __restrict__ out)
{
    __shared__ float lsum[4];
    const int tid = threadIdx.x;
    float s = 0.f;
    for (int i = tid; i < NBLK; i += 256) s += lossp[i];
    s += __shfl_down(s, 32); s += __shfl_down(s, 16);
    s += __shfl_down(s, 8);  s += __shfl_down(s, 4);
    s += __shfl_down(s, 2);  s += __shfl_down(s, 1);
    const int wv = tid >> 6, l = tid & 63;
    if (l == 0) lsum[wv] = s;
    __syncthreads();
    if (tid == 0)
        out[LOSS_OFF] = ((lsum[0] + lsum[1]) + (lsum[2] + lsum[3])) * (2.0f / (float)(NTOK * D_));
}

// ---------- fallback (round-1 monolithic) ----------
__global__ __launch_bounds__(256)
void vq_mono(const float* __restrict__ z,  const float* __restrict__ qw,
             const float* __restrict__ qb, const float* __restrict__ cb,
             const float* __restrict__ pw, const float* __restrict__ pb,
             float* __restrict__ out)
{
    __shared__ float cbn_s[K_];
    __shared__ float lsum[4];
    const int tid = threadIdx.x;
    for (int k = tid; k < K_; k += 256) {
        const float* row = cb + k * D_;
        float s = 0.f;
        #pragma unroll
        for (int d = 0; d < D_; ++d) s = fmaf(row[d], row[d], s);
        cbn_s[k] = s;
    }
    __syncthreads();
    const int token = blockIdx.x * 256 + tid;
    const int b = token >> 12, hw = token & (HW_ - 1);
    const float* zbase = z + (size_t)b * C_ * HW_ + hw;
    float zv[C_];
    #pragma unroll
    for (int c = 0; c < C_; ++c) zv[c] = zbase[(size_t)c * HW_];
    float xf[D_];
    #pragma unroll
    for (int d = 0; d < D_; ++d) {
        float a = qb[d];
        #pragma unroll
        for (int c = 0; c < C_; ++c) a = fmaf(zv[c], qw[d * C_ + c], a);
        xf[d] = a;
    }
    float best = 3.4e38f; int bi = 0;
    #pragma unroll 2
    for (int k = 0; k < K_; ++k) {
        const float* row = cb + k * D_;
        float p0 = 0.f, p1 = 0.f, p2 = 0.f, p3 = 0.f;
        #pragma unroll
        for (int d = 0; d < D_; d += 4) {
            p0 = fmaf(xf[d+0], row[d+0], p0); p1 = fmaf(xf[d+1], row[d+1], p1);
            p2 = fmaf(xf[d+2], row[d+2], p2); p3 = fmaf(xf[d+3], row[d+3], p3);
        }
        const float s = fmaf(-2.f, (p0+p1)+(p2+p3), cbn_s[k]);
        if (s < best) { best = s; bi = k; }
    }
    out[IDX_OFF + token] = (float)bi;
    const float* qrow = cb + (size_t)bi * D_;
    float qv[D_];
    #pragma unroll
    for (int d = 0; d < D_; ++d) qv[d] = qrow[d];
    float l = 0.f;
    #pragma unroll
    for (int d = 0; d < D_; ++d) { const float df = qv[d] - xf[d]; l = fmaf(df, df, l); }
    float* obase = out + (size_t)b * C_ * HW_ + hw;
    #pragma unroll
    for (int c = 0; c < C_; ++c) {
        float a = pb[c];
        #pragma unroll
        for (int d = 0; d < D_; ++d) a = fmaf(qv[d], pw[c * D_ + d], a);
        obase[(size_t)c * HW_] = a;
    }
    #pragma unroll
    for (int off = 32; off; off >>= 1) l += __shfl_down(l, off);
    const int wid = tid >> 6, lane = tid & 63;
    if (lane == 0) lsum[wid] = l;
    __syncthreads();
    if (tid == 0) {
        const float t = (lsum[0] + lsum[1]) + (lsum[2] + lsum[3]);
        atomicAdd(out + LOSS_OFF, t * (2.0f / (float)(NTOK * D_)));
    }
}

extern "C" void kernel_launch(void* const* d_in, const int* in_sizes, int n_in,
                              void* d_out, int out_size, void* d_ws, size_t ws_size,
                              hipStream_t stream) {
    (void)in_sizes; (void)n_in; (void)out_size;
    const float* z  = (const float*)d_in[0];
    const float* qw = (const float*)d_in[1];
    const float* qb = (const float*)d_in[2];
    const float* cb = (const float*)d_in[3];
    const float* pw = (const float*)d_in[4];
    const float* pb = (const float*)d_in[5];
    float* out = (float*)d_out;

    if (ws_size < (size_t)WS_NEEDED) {
        hipMemsetAsync((char*)d_out + (size_t)LOSS_OFF * sizeof(float), 0, sizeof(float), stream);
        vq_mono<<<NTOK / 256, 256, 0, stream>>>(z, qw, qb, cb, pw, pb, out);
        return;
    }
    char* ws = (char*)d_ws;
    float*          cbn   = (float*)(ws + WS_CBN);
    unsigned short* cbh   = (unsigned short*)(ws + WS_CBH);
    unsigned short* cbl   = (unsigned short*)(ws + WS_CBL);
    float*          lossp = (float*)(ws + WS_LOSSP);

    prep_cb<<<2, 256, 0, stream>>>(cb, cbn, cbh, cbl);
    vq_fused<<<NBLK, 256, 0, stream>>>(z, qw, qb, cb, pw, pb, cbh, cbl, cbn, lossp, out);
    loss_final<<<1, 256, 0, stream>>>(lossp, out);
}

// Round 8
// 107.486 us; speedup vs baseline: 1.1352x; 1.1352x over previous
//
#include <hip/hip_runtime.h>

// (B,C,H,W)=(32,32,64,64), D=32, K=512
#define C_    32
#define D_    32
#define K_    512
#define HW_   4096
#define NTOK  131072
#define IDX_OFF   4194304
#define LOSS_OFF  4325376
#define TAU   2e-3f
#define NBLK  4096               // 32-token tiles, 1 wave each

// ws: cbn @0, cbh @4096, cbl @36864, lossp @69632 (NBLK f32)
#define WS_CBN   0
#define WS_CBH   4096
#define WS_CBL   36864
#define WS_LOSSP 69632
#define WS_NEEDED (69632 + NBLK * 4)

typedef __attribute__((ext_vector_type(8))) __bf16 bf16x8;
typedef __attribute__((ext_vector_type(8))) short  short8;
typedef __attribute__((ext_vector_type(4))) float  f32x4;

__device__ inline unsigned short f2bf(float x) {          // RNE fp32->bf16
    unsigned u = __builtin_bit_cast(unsigned, x);
    return (unsigned short)((u + 0x7FFFu + ((u >> 16) & 1u)) >> 16);
}
__device__ inline float bf2f(unsigned short h) {
    unsigned u = ((unsigned)h) << 16; return __builtin_bit_cast(float, u);
}

// ---------- codebook split + norms ----------
__global__ __launch_bounds__(256)
void prep_cb(const float* __restrict__ cb, float* __restrict__ cbn,
             unsigned short* __restrict__ cbh, unsigned short* __restrict__ cbl)
{
    const int k = blockIdx.x * 256 + threadIdx.x;   // grid=2
    const float* row = cb + k * D_;
    float s = 0.f;
    unsigned short h[32], lo[32];
    #pragma unroll
    for (int d = 0; d < D_; ++d) {
        const float v = row[d]; s = fmaf(v, v, s);
        const unsigned short hh = f2bf(v);
        h[d] = hh; lo[d] = f2bf(v - bf2f(hh));
    }
    cbn[k] = s;
    #pragma unroll
    for (int j = 0; j < 4; ++j) {
        *(short8*)(cbh + k * 32 + 8 * j) = *(const short8*)(h  + 8 * j);
        *(short8*)(cbl + k * 32 + 8 * j) = *(const short8*)(lo + 8 * j);
    }
}

// ---------- wave-autonomous fused kernel: 1 wave = 32 tokens, full 512-code scan ----------
__global__ __launch_bounds__(64, 4)
void vq_fused(const float* __restrict__ z,  const float* __restrict__ qw,
              const float* __restrict__ qb, const float* __restrict__ cb,
              const float* __restrict__ pw, const float* __restrict__ pb,
              const unsigned short* __restrict__ cbh, const unsigned short* __restrict__ cbl,
              const float* __restrict__ cbn, float* __restrict__ lossp,
              float* __restrict__ out)
{
    __shared__ float xsh[32][33];
    __shared__ float qsh[32][33];
    __shared__ int   sidx[32];

    const int l = threadIdx.x;                    // 0..63, single wave
    const int bid = blockIdx.x;
    const int swz = (bid & 7) * 512 + (bid >> 3); // XCD-contiguous tiles (bijective)
    const int T0 = swz * 32;
    const int b = T0 >> 12, hw0 = T0 & (HW_ - 1);
    const int tok = l & 31, half = l >> 5;

    // ---- phase 1: quant conv (2 lanes/token, 16 d-channels each) ----
    {
        const float* zbase = z + (size_t)b * (C_ * HW_) + hw0 + tok;
        float zv[C_];
        #pragma unroll
        for (int c = 0; c < C_; ++c) zv[c] = zbase[(size_t)c * HW_];
        const int d0 = half * 16;
        float acc[16];
        #pragma unroll
        for (int i = 0; i < 16; ++i) acc[i] = qb[d0 + i];
        #pragma unroll
        for (int i = 0; i < 16; ++i) {
            const float4* qr = (const float4*)(qw + (d0 + i) * C_);
            #pragma unroll
            for (int c4 = 0; c4 < 8; ++c4) {
                const float4 q4 = qr[c4];
                acc[i] = fmaf(zv[4*c4+0], q4.x, acc[i]);
                acc[i] = fmaf(zv[4*c4+1], q4.y, acc[i]);
                acc[i] = fmaf(zv[4*c4+2], q4.z, acc[i]);
                acc[i] = fmaf(zv[4*c4+3], q4.w, acc[i]);
            }
        }
        #pragma unroll
        for (int i = 0; i < 16; ++i) xsh[tok][d0 + i] = acc[i];
    }
    __syncthreads();   // 1-wave block: pure LDS fence, no cross-wave wait

    // ---- A fragments (row=lane&15 token, k-chunk=(lane>>4)*8), bf16 hi/lo split ----
    const int lr = l & 15, lg = l >> 4;
    short8 sh0, sl0, sh1, sl1;
    #pragma unroll
    for (int j = 0; j < 8; ++j) {
        const float v0 = xsh[lr][lg * 8 + j];
        const float v1 = xsh[16 + lr][lg * 8 + j];
        const unsigned short h0 = f2bf(v0), h1 = f2bf(v1);
        sh0[j] = (short)h0; sl0[j] = (short)f2bf(v0 - bf2f(h0));
        sh1[j] = (short)h1; sl1[j] = (short)f2bf(v1 - bf2f(h1));
    }
    const bf16x8 ah0 = __builtin_bit_cast(bf16x8, sh0);
    const bf16x8 al0 = __builtin_bit_cast(bf16x8, sl0);
    const bf16x8 ah1 = __builtin_bit_cast(bf16x8, sh1);
    const bf16x8 al1 = __builtin_bit_cast(bf16x8, sl1);

    // ---- phase 2: MFMA top-2 scan, 32 iters, software-prefetched B rows ----
    const unsigned short* pbh = cbh + (size_t)lr * 32 + lg * 8;   // + nt*512 shorts/iter
    const unsigned short* pbl = cbl + (size_t)lr * 32 + lg * 8;
    short8 nbh = *(const short8*)pbh;
    short8 nbl = *(const short8*)pbl;
    float  ncn = cbn[lr];

    float b1[8], b2[8]; int i1[8];
    #pragma unroll
    for (int s = 0; s < 8; ++s) { b1[s] = 3.4e38f; b2[s] = 3.4e38f; i1[s] = 0; }

    #pragma unroll 4
    for (int nt = 0; nt < 32; ++nt) {
        const bf16x8 bh = __builtin_bit_cast(bf16x8, nbh);
        const bf16x8 bl = __builtin_bit_cast(bf16x8, nbl);
        const float  cn = ncn;
        // prefetch next iteration's rows (overruns into ws scratch on last iter; unused)
        nbh = *(const short8*)(pbh + (size_t)(nt + 1) * 512);
        nbl = *(const short8*)(pbl + (size_t)(nt + 1) * 512);
        ncn = cbn[(nt + 1) * 16 + lr];

        f32x4 acc0 = {0.f,0.f,0.f,0.f}, acc1 = {0.f,0.f,0.f,0.f};
        acc0 = __builtin_amdgcn_mfma_f32_16x16x32_bf16(ah0, bh, acc0, 0, 0, 0);
        acc0 = __builtin_amdgcn_mfma_f32_16x16x32_bf16(ah0, bl, acc0, 0, 0, 0);
        acc0 = __builtin_amdgcn_mfma_f32_16x16x32_bf16(al0, bh, acc0, 0, 0, 0);
        acc1 = __builtin_amdgcn_mfma_f32_16x16x32_bf16(ah1, bh, acc1, 0, 0, 0);
        acc1 = __builtin_amdgcn_mfma_f32_16x16x32_bf16(ah1, bl, acc1, 0, 0, 0);
        acc1 = __builtin_amdgcn_mfma_f32_16x16x32_bf16(al1, bh, acc1, 0, 0, 0);
        const int n = nt * 16 + lr;
        #pragma unroll
        for (int r = 0; r < 4; ++r) {
            {
                const float d2 = fmaf(-2.f, acc0[r], cn);
                const bool lt1 = d2 < b1[r], lt2 = d2 < b2[r];
                b2[r] = lt1 ? b1[r] : (lt2 ? d2 : b2[r]);
                b1[r] = lt1 ? d2 : b1[r];
                i1[r] = lt1 ? n  : i1[r];
            }
            {
                const float d2 = fmaf(-2.f, acc1[r], cn);
                const bool lt1 = d2 < b1[4+r], lt2 = d2 < b2[4+r];
                b2[4+r] = lt1 ? b1[4+r] : (lt2 ? d2 : b2[4+r]);
                b1[4+r] = lt1 ? d2 : b1[4+r];
                i1[4+r] = lt1 ? n  : i1[4+r];
            }
        }
    }
    // merge top-2 across the 16 n-lanes of each lg group
    #pragma unroll
    for (int mk = 1; mk < 16; mk <<= 1) {
        #pragma unroll
        for (int s = 0; s < 8; ++s) {
            const float ob1 = __shfl_xor(b1[s], mk);
            const int   oi1 = __shfl_xor(i1[s], mk);
            const float ob2 = __shfl_xor(b2[s], mk);
            const bool take = (ob1 < b1[s]) || (ob1 == b1[s] && oi1 < i1[s]);
            const float loser = take ? b1[s] : ob1;
            b1[s] = take ? ob1 : b1[s];
            i1[s] = take ? oi1 : i1[s];
            b2[s] = fminf(fminf(b2[s], ob2), loser);
        }
    }
    #pragma unroll
    for (int s = 0; s < 8; ++s) {
        if (lr == s) {
            const int tokW = (s >> 2) * 16 + lg * 4 + (s & 3);
            sidx[tokW] = i1[s] | (((b2[s] - b1[s]) < TAU) ? 512 : 0);
        }
    }
    __syncthreads();

    // ---- phase 3: exact fp32 rescan of flagged tokens (rare, in-wave) ----
    {
        const int sv = sidx[tok];
        unsigned long long m = __ballot((l < 32) && (sv & 512));
        while (m) {
            const int j = __ffsll(m) - 1; m &= m - 1;
            float xfj[D_];
            #pragma unroll
            for (int d = 0; d < D_; ++d) xfj[d] = xsh[j][d];
            float bb = 3.4e38f; int bi = 0;
            #pragma unroll
            for (int p = 0; p < 8; ++p) {
                const int c = l + 64 * p;
                const float* row = cb + (size_t)c * D_;
                float p0 = 0.f, p1 = 0.f, p2 = 0.f, p3 = 0.f;
                #pragma unroll
                for (int d = 0; d < D_; d += 4) {
                    p0 = fmaf(xfj[d],   row[d],   p0); p1 = fmaf(xfj[d+1], row[d+1], p1);
                    p2 = fmaf(xfj[d+2], row[d+2], p2); p3 = fmaf(xfj[d+3], row[d+3], p3);
                }
                const float dd = fmaf(-2.f, (p0 + p1) + (p2 + p3), cbn[c]);
                if (dd < bb) { bb = dd; bi = c; }
            }
            #pragma unroll
            for (int s = 1; s < 64; s <<= 1) {
                const float ob = __shfl_xor(bb, s); const int oi = __shfl_xor(bi, s);
                if (ob < bb || (ob == bb && oi < bi)) { bb = ob; bi = oi; }
            }
            if (l == j) sidx[j] = bi;
        }
    }
    __syncthreads();
    const int myidx = sidx[tok] & 511;

    // ---- phase 4: gather, loss, idx write, post conv ----
    float qreg[16];
    {
        const float4* qrow = (const float4*)(cb + (size_t)myidx * D_ + half * 16);
        #pragma unroll
        for (int d4 = 0; d4 < 4; ++d4) {
            const float4 t = qrow[d4];
            qreg[4*d4+0] = t.x; qreg[4*d4+1] = t.y; qreg[4*d4+2] = t.z; qreg[4*d4+3] = t.w;
        }
        #pragma unroll
        for (int i = 0; i < 16; ++i) qsh[tok][half * 16 + i] = qreg[i];
    }
    float lacc = 0.f;
    #pragma unroll
    for (int i = 0; i < 16; ++i) {
        const float df = qreg[i] - xsh[tok][half * 16 + i];
        lacc = fmaf(df, df, lacc);
    }
    lacc += __shfl_down(lacc, 32);   // full-token sums in lanes 0..31
    lacc += __shfl_down(lacc, 16); lacc += __shfl_down(lacc, 8);
    lacc += __shfl_down(lacc, 4);  lacc += __shfl_down(lacc, 2);
    lacc += __shfl_down(lacc, 1);
    if (l == 0) lossp[bid] = lacc;

    if (l < 32) out[IDX_OFF + T0 + l] = (float)(sidx[l] & 511);
    __syncthreads();   // qsh ready

    {
        const int c0 = half * 16;
        float a[16];
        #pragma unroll
        for (int i = 0; i < 16; ++i) a[i] = pb[c0 + i];
        #pragma unroll
        for (int d4 = 0; d4 < 8; ++d4) {
            const float q0 = qsh[tok][d4*4+0], q1 = qsh[tok][d4*4+1];
            const float q2 = qsh[tok][d4*4+2], q3 = qsh[tok][d4*4+3];
            #pragma unroll
            for (int i = 0; i < 16; ++i) {
                const float4 p4 = *(const float4*)(pw + (c0 + i) * D_ + d4 * 4);
                a[i] = fmaf(q0, p4.x, a[i]); a[i] = fmaf(q1, p4.y, a[i]);
                a[i] = fmaf(q2, p4.z, a[i]); a[i] = fmaf(q3, p4.w, a[i]);
            }
        }
        float* obase = out + (size_t)b * (C_ * HW_) + hw0 + tok;
        #pragma unroll
        for (int i = 0; i < 16; ++i) obase[(size_t)(c0 + i) * HW_] = a[i];
    }
}

// ---------- loss finalize (single block) ----------
__global__ __launch_bounds__(256)
void loss_final(const float* __restrict__ lossp, float* __restrict__ out)
{
    __shared__ float lsum[4];
    const int tid = threadIdx.x;
    float s = 0.f;
    for (int i = tid; i < NBLK; i += 256) s += lossp[i];
    s += __shfl_down(s, 32); s += __shfl_down(s, 16);
    s += __shfl_down(s, 8);  s += __shfl_down(s, 4);
    s += __shfl_down(s, 2);  s += __shfl_down(s, 1);
    const int wv = tid >> 6, l = tid & 63;
    if (l == 0) lsum[wv] = s;
    __syncthreads();
    if (tid == 0)
        out[LOSS_OFF] = ((lsum[0] + lsum[1]) + (lsum[2] + lsum[3])) * (2.0f / (float)(NTOK * D_));
}

// ---------- fallback (round-1 monolithic) ----------
__global__ __launch_bounds__(256)
void vq_mono(const float* __restrict__ z,  const float* __restrict__ qw,
             const float* __restrict__ qb, const float* __restrict__ cb,
             const float* __restrict__ pw, const float* __restrict__ pb,
             float* __restrict__ out)
{
    __shared__ float cbn_s[K_];
    __shared__ float lsum[4];
    const int tid = threadIdx.x;
    for (int k = tid; k < K_; k += 256) {
        const float* row = cb + k * D_;
        float s = 0.f;
        #pragma unroll
        for (int d = 0; d < D_; ++d) s = fmaf(row[d], row[d], s);
        cbn_s[k] = s;
    }
    __syncthreads();
    const int token = blockIdx.x * 256 + tid;
    const int b = token >> 12, hw = token & (HW_ - 1);
    const float* zbase = z + (size_t)b * C_ * HW_ + hw;
    float zv[C_];
    #pragma unroll
    for (int c = 0; c < C_; ++c) zv[c] = zbase[(size_t)c * HW_];
    float xf[D_];
    #pragma unroll
    for (int d = 0; d < D_; ++d) {
        float a = qb[d];
        #pragma unroll
        for (int c = 0; c < C_; ++c) a = fmaf(zv[c], qw[d * C_ + c], a);
        xf[d] = a;
    }
    float best = 3.4e38f; int bi = 0;
    #pragma unroll 2
    for (int k = 0; k < K_; ++k) {
        const float* row = cb + k * D_;
        float p0 = 0.f, p1 = 0.f, p2 = 0.f, p3 = 0.f;
        #pragma unroll
        for (int d = 0; d < D_; d += 4) {
            p0 = fmaf(xf[d+0], row[d+0], p0); p1 = fmaf(xf[d+1], row[d+1], p1);
            p2 = fmaf(xf[d+2], row[d+2], p2); p3 = fmaf(xf[d+3], row[d+3], p3);
        }
        const float s = fmaf(-2.f, (p0+p1)+(p2+p3), cbn_s[k]);
        if (s < best) { best = s; bi = k; }
    }
    out[IDX_OFF + token] = (float)bi;
    const float* qrow = cb + (size_t)bi * D_;
    float qv[D_];
    #pragma unroll
    for (int d = 0; d < D_; ++d) qv[d] = qrow[d];
    float l = 0.f;
    #pragma unroll
    for (int d = 0; d < D_; ++d) { const float df = qv[d] - xf[d]; l = fmaf(df, df, l); }
    float* obase = out + (size_t)b * C_ * HW_ + hw;
    #pragma unroll
    for (int c = 0; c < C_; ++c) {
        float a = pb[c];
        #pragma unroll
        for (int d = 0; d < D_; ++d) a = fmaf(qv[d], pw[c * D_ + d], a);
        obase[(size_t)c * HW_] = a;
    }
    #pragma unroll
    for (int off = 32; off; off >>= 1) l += __shfl_down(l, off);
    const int wid = tid >> 6, lane = tid & 63;
    if (lane == 0) lsum[wid] = l;
    __syncthreads();
    if (tid == 0) {
        const float t = (lsum[0] + lsum[1]) + (lsum[2] + lsum[3]);
        atomicAdd(out + LOSS_OFF, t * (2.0f / (float)(NTOK * D_)));
    }
}

extern "C" void kernel_launch(void* const* d_in, const int* in_sizes, int n_in,
                              void* d_out, int out_size, void* d_ws, size_t ws_size,
                              hipStream_t stream) {
    (void)in_sizes; (void)n_in; (void)out_size;
    const float* z  = (const float*)d_in[0];
    const float* qw = (const float*)d_in[1];
    const float* qb = (const float*)d_in[2];
    const float* cb = (const float*)d_in[3];
    const float* pw = (const float*)d_in[4];
    const float* pb = (const float*)d_in[5];
    float* out = (float*)d_out;

    if (ws_size < (size_t)WS_NEEDED) {
        hipMemsetAsync((char*)d_out + (size_t)LOSS_OFF * sizeof(float), 0, sizeof(float), stream);
        vq_mono<<<NTOK / 256, 256, 0, stream>>>(z, qw, qb, cb, pw, pb, out);
        return;
    }
    char* ws = (char*)d_ws;
    float*          cbn   = (float*)(ws + WS_CBN);
    unsigned short* cbh   = (unsigned short*)(ws + WS_CBH);
    unsigned short* cbl   = (unsigned short*)(ws + WS_CBL);
    float*          lossp = (float*)(ws + WS_LOSSP);

    prep_cb<<<2, 256, 0, stream>>>(cb, cbn, cbh, cbl);
    vq_fused<<<NBLK, 64, 0, stream>>>(z, qw, qb, cb, pw, pb, cbh, cbl, cbn, lossp, out);
    loss_final<<<1, 256, 0, stream>>>(lossp, out);
}

// Round 9
// 81.872 us; speedup vs baseline: 1.4904x; 1.3128x over previous
//
#include <hip/hip_runtime.h>

// (B,C,H,W)=(32,32,64,64), D=32, K=512
#define C_    32
#define D_    32
#define K_    512
#define HW_   4096
#define NTOK  131072
#define IDX_OFF   4194304
#define LOSS_OFF  4325376
#define TAU   2e-4f

// ws: cbn @0 (2KB), cbhf @4096 (32KB frag-major f16 hi), cblf @36864 (32KB lo), lossp @69632 (16KB)
#define WS_CBN   0
#define WS_CBHF  4096
#define WS_CBLF  36864
#define WS_LOSSP 69632
#define WS_NEEDED 86016

typedef __attribute__((ext_vector_type(8))) _Float16 f16x8;
typedef __attribute__((ext_vector_type(8))) short    short8;
typedef __attribute__((ext_vector_type(4))) float    f32x4;

#define WAVE_FENCE() do { asm volatile("s_waitcnt lgkmcnt(0)" ::: "memory"); \
                          __builtin_amdgcn_sched_barrier(0); } while (0)

__device__ inline short f2h_hi(float v, float* rest) {
    const _Float16 h = (_Float16)v;
    *rest = v - (float)h;
    return __builtin_bit_cast(short, h);
}

// ---------- codebook: norms + f16 hi/lo split in FRAG-MAJOR layout ----------
// scan lane l at iter nt reads shorts [nt*512 + l*8 .. +8] == code row nt*16+(l&15), chunk l>>4
__global__ __launch_bounds__(256)
void prep_cb(const float* __restrict__ cb, float* __restrict__ cbn,
             short* __restrict__ cbhf, short* __restrict__ cblf)
{
    const int k = blockIdx.x * 256 + threadIdx.x;   // grid=2 -> k in [0,512)
    const int nt = k >> 4, lr = k & 15;
    const float* row = cb + k * D_;
    float s = 0.f;
    short h[32], lo[32];
    #pragma unroll
    for (int d = 0; d < D_; ++d) {
        const float v = row[d]; s = fmaf(v, v, s);
        float r; h[d] = f2h_hi(v, &r);
        lo[d] = __builtin_bit_cast(short, (_Float16)r);
    }
    cbn[k] = s;
    #pragma unroll
    for (int j = 0; j < 4; ++j) {   // chunk j -> frag-major slot (j*16+lr) of iter-block nt
        *(short8*)(cbhf + nt * 512 + (j * 16 + lr) * 8) = *(const short8*)(h  + 8 * j);
        *(short8*)(cblf + nt * 512 + (j * 16 + lr) * 8) = *(const short8*)(lo + 8 * j);
    }
}

// ---------- fused: 512 thr = 8 autonomous waves x 32 tokens; LDS-resident codebook ----------
__global__ __launch_bounds__(512, 2)
void vq_fused(const float* __restrict__ z,  const float* __restrict__ qw,
              const float* __restrict__ qb, const float* __restrict__ cb,
              const float* __restrict__ pw, const float* __restrict__ pb,
              const short* __restrict__ cbhf, const short* __restrict__ cblf,
              const float* __restrict__ cbn, float* __restrict__ lossp,
              float* __restrict__ out)
{
    __shared__ __align__(16) short cbh_s[16384];   // 32 KB frag-major
    __shared__ __align__(16) short cbl_s[16384];   // 32 KB
    __shared__ float cbn_s[K_];
    __shared__ float xsh[8][32][33];
    __shared__ int   sidx[8][32];

    const int tid = threadIdx.x;
    const int wv = tid >> 6, l = tid & 63;

    // ---- stage codebook to LDS (once per block) ----
    #pragma unroll
    for (int i = 0; i < 4; ++i)
        ((float4*)cbh_s)[tid + 512 * i] = ((const float4*)cbhf)[tid + 512 * i];
    #pragma unroll
    for (int i = 0; i < 4; ++i)
        ((float4*)cbl_s)[tid + 512 * i] = ((const float4*)cblf)[tid + 512 * i];
    if (tid < K_) cbn_s[tid] = cbn[tid];
    __syncthreads();   // the only block-wide barrier

    const int T0 = (blockIdx.x * 8 + wv) * 32;
    const int b = T0 >> 12, hw0 = T0 & (HW_ - 1);
    const int tok = l & 31, half = l >> 5;

    // ---- phase 1: quant conv (2 lanes/token, 16 d-channels each) ----
    {
        const float* zbase = z + (size_t)b * (C_ * HW_) + hw0 + tok;
        float zv[C_];
        #pragma unroll
        for (int c = 0; c < C_; ++c) zv[c] = zbase[(size_t)c * HW_];
        const int d0 = half * 16;
        #pragma unroll
        for (int i = 0; i < 16; ++i) {
            float a = qb[d0 + i];
            const float4* qr = (const float4*)(qw + (d0 + i) * C_);
            #pragma unroll
            for (int c4 = 0; c4 < 8; ++c4) {
                const float4 q4 = qr[c4];
                a = fmaf(zv[4*c4+0], q4.x, a); a = fmaf(zv[4*c4+1], q4.y, a);
                a = fmaf(zv[4*c4+2], q4.z, a); a = fmaf(zv[4*c4+3], q4.w, a);
            }
            xsh[wv][tok][d0 + i] = a;
        }
    }
    WAVE_FENCE();   // same-wave LDS visibility

    // ---- A fragments (row=lane&15 token, k-chunk=(lane>>4)*8), f16 hi/lo split ----
    const int lr = l & 15, lg = l >> 4;
    short8 sh0, sl0, sh1, sl1;
    #pragma unroll
    for (int j = 0; j < 8; ++j) {
        float r0, r1;
        sh0[j] = f2h_hi(xsh[wv][lr][lg * 8 + j], &r0);
        sl0[j] = __builtin_bit_cast(short, (_Float16)r0);
        sh1[j] = f2h_hi(xsh[wv][16 + lr][lg * 8 + j], &r1);
        sl1[j] = __builtin_bit_cast(short, (_Float16)r1);
    }
    const f16x8 ah0 = __builtin_bit_cast(f16x8, sh0);
    const f16x8 al0 = __builtin_bit_cast(f16x8, sl0);
    const f16x8 ah1 = __builtin_bit_cast(f16x8, sh1);
    const f16x8 al1 = __builtin_bit_cast(f16x8, sl1);

    // ---- phase 2: MFMA top-2 scan over 512 codes, B from LDS ----
    float b1[8], b2[8]; int i1[8];
    #pragma unroll
    for (int s = 0; s < 8; ++s) { b1[s] = 3.4e38f; b2[s] = 3.4e38f; i1[s] = 0; }

    #pragma unroll 2
    for (int nt = 0; nt < 32; ++nt) {
        const f16x8 bh = __builtin_bit_cast(f16x8, *(const short8*)(cbh_s + nt * 512 + l * 8));
        const f16x8 bl = __builtin_bit_cast(f16x8, *(const short8*)(cbl_s + nt * 512 + l * 8));
        const float cn = cbn_s[nt * 16 + lr];
        f32x4 acc0 = {0.f,0.f,0.f,0.f}, acc1 = {0.f,0.f,0.f,0.f};
        acc0 = __builtin_amdgcn_mfma_f32_16x16x32_f16(ah0, bh, acc0, 0, 0, 0);
        acc0 = __builtin_amdgcn_mfma_f32_16x16x32_f16(ah0, bl, acc0, 0, 0, 0);
        acc0 = __builtin_amdgcn_mfma_f32_16x16x32_f16(al0, bh, acc0, 0, 0, 0);
        acc1 = __builtin_amdgcn_mfma_f32_16x16x32_f16(ah1, bh, acc1, 0, 0, 0);
        acc1 = __builtin_amdgcn_mfma_f32_16x16x32_f16(ah1, bl, acc1, 0, 0, 0);
        acc1 = __builtin_amdgcn_mfma_f32_16x16x32_f16(al1, bh, acc1, 0, 0, 0);
        const int n = nt * 16 + lr;
        #pragma unroll
        for (int r = 0; r < 4; ++r) {
            {
                const float d2 = fmaf(-2.f, acc0[r], cn);
                const bool lt1 = d2 < b1[r], lt2 = d2 < b2[r];
                b2[r] = lt1 ? b1[r] : (lt2 ? d2 : b2[r]);
                b1[r] = lt1 ? d2 : b1[r];
                i1[r] = lt1 ? n  : i1[r];
            }
            {
                const float d2 = fmaf(-2.f, acc1[r], cn);
                const bool lt1 = d2 < b1[4+r], lt2 = d2 < b2[4+r];
                b2[4+r] = lt1 ? b1[4+r] : (lt2 ? d2 : b2[4+r]);
                b1[4+r] = lt1 ? d2 : b1[4+r];
                i1[4+r] = lt1 ? n  : i1[4+r];
            }
        }
    }
    // merge top-2 across the 16 n-lanes of each lg group
    #pragma unroll
    for (int mk = 1; mk < 16; mk <<= 1) {
        #pragma unroll
        for (int s = 0; s < 8; ++s) {
            const float ob1 = __shfl_xor(b1[s], mk);
            const int   oi1 = __shfl_xor(i1[s], mk);
            const float ob2 = __shfl_xor(b2[s], mk);
            const bool take = (ob1 < b1[s]) || (ob1 == b1[s] && oi1 < i1[s]);
            const float loser = take ? b1[s] : ob1;
            b1[s] = take ? ob1 : b1[s];
            i1[s] = take ? oi1 : i1[s];
            b2[s] = fminf(fminf(b2[s], ob2), loser);
        }
    }
    #pragma unroll
    for (int s = 0; s < 8; ++s) {
        if (lr == s) {
            const int tokW = (s >> 2) * 16 + lg * 4 + (s & 3);
            sidx[wv][tokW] = i1[s] | (((b2[s] - b1[s]) < TAU) ? 512 : 0);
        }
    }
    WAVE_FENCE();

    // ---- phase 3: exact fp32 rescan of flagged tokens (rare, in-wave) ----
    {
        const int sv = sidx[wv][tok];
        unsigned long long m = __ballot((l < 32) && (sv & 512));
        while (m) {
            const int j = __ffsll(m) - 1; m &= m - 1;
            float xfj[D_];
            #pragma unroll
            for (int d = 0; d < D_; ++d) xfj[d] = xsh[wv][j][d];
            float bb = 3.4e38f; int bi = 0;
            #pragma unroll
            for (int p = 0; p < 8; ++p) {
                const int c = l + 64 * p;
                const float* row = cb + (size_t)c * D_;
                float p0 = 0.f, p1 = 0.f, p2 = 0.f, p3 = 0.f;
                #pragma unroll
                for (int d = 0; d < D_; d += 4) {
                    p0 = fmaf(xfj[d],   row[d],   p0); p1 = fmaf(xfj[d+1], row[d+1], p1);
                    p2 = fmaf(xfj[d+2], row[d+2], p2); p3 = fmaf(xfj[d+3], row[d+3], p3);
                }
                const float dd = fmaf(-2.f, (p0 + p1) + (p2 + p3), cbn_s[c]);
                if (dd < bb) { bb = dd; bi = c; }
            }
            #pragma unroll
            for (int s = 1; s < 64; s <<= 1) {
                const float ob = __shfl_xor(bb, s); const int oi = __shfl_xor(bi, s);
                if (ob < bb || (ob == bb && oi < bi)) { bb = ob; bi = oi; }
            }
            if (l == j) sidx[wv][j] = bi;
        }
    }
    WAVE_FENCE();
    const int myidx = sidx[wv][tok] & 511;

    // ---- phase 4: gather, loss, idx write, post conv ----
    if (l < 32) out[IDX_OFF + T0 + l] = (float)(sidx[wv][l] & 511);

    float qreg[16];
    {
        const float4* qrow = (const float4*)(cb + (size_t)myidx * D_ + half * 16);
        #pragma unroll
        for (int d4 = 0; d4 < 4; ++d4) {
            const float4 t = qrow[d4];
            qreg[4*d4+0] = t.x; qreg[4*d4+1] = t.y; qreg[4*d4+2] = t.z; qreg[4*d4+3] = t.w;
        }
    }
    float lacc = 0.f;
    #pragma unroll
    for (int i = 0; i < 16; ++i) {
        const float df = qreg[i] - xsh[wv][tok][half * 16 + i];
        lacc = fmaf(df, df, lacc);
    }
    lacc += __shfl_down(lacc, 32);
    lacc += __shfl_down(lacc, 16); lacc += __shfl_down(lacc, 8);
    lacc += __shfl_down(lacc, 4);  lacc += __shfl_down(lacc, 2);
    lacc += __shfl_down(lacc, 1);
    if (l == 0) lossp[blockIdx.x * 8 + wv] = lacc;

    // overwrite this wave's xsh tile with q, then post-conv from it
    #pragma unroll
    for (int i = 0; i < 16; ++i) xsh[wv][tok][half * 16 + i] = qreg[i];
    WAVE_FENCE();

    {
        const int c0 = half * 16;
        float a[16];
        #pragma unroll
        for (int i = 0; i < 16; ++i) a[i] = pb[c0 + i];
        #pragma unroll
        for (int d4 = 0; d4 < 8; ++d4) {
            const float q0 = xsh[wv][tok][d4*4+0], q1 = xsh[wv][tok][d4*4+1];
            const float q2 = xsh[wv][tok][d4*4+2], q3 = xsh[wv][tok][d4*4+3];
            #pragma unroll
            for (int i = 0; i < 16; ++i) {
                const float4 p4 = *(const float4*)(pw + (c0 + i) * D_ + d4 * 4);
                a[i] = fmaf(q0, p4.x, a[i]); a[i] = fmaf(q1, p4.y, a[i]);
                a[i] = fmaf(q2, p4.z, a[i]); a[i] = fmaf(q3, p4.w, a[i]);
            }
        }
        float* obase = out + (size_t)b * (C_ * HW_) + hw0 + tok;
        #pragma unroll
        for (int i = 0; i < 16; ++i) obase[(size_t)(c0 + i) * HW_] = a[i];
    }
}

// ---------- loss finalize (single block) ----------
__global__ __launch_bounds__(256)
void loss_final(const float* __restrict__ lossp, float* __restrict__ out)
{
    __shared__ float lsum[4];
    const int tid = threadIdx.x;
    float s = 0.f;
    for (int i = tid; i < 4096; i += 256) s += lossp[i];
    s += __shfl_down(s, 32); s += __shfl_down(s, 16);
    s += __shfl_down(s, 8);  s += __shfl_down(s, 4);
    s += __shfl_down(s, 2);  s += __shfl_down(s, 1);
    const int wv = tid >> 6, l = tid & 63;
    if (l == 0) lsum[wv] = s;
    __syncthreads();
    if (tid == 0)
        out[LOSS_OFF] = ((lsum[0] + lsum[1]) + (lsum[2] + lsum[3])) * (2.0f / (float)(NTOK * D_));
}

// ---------- fallback (round-1 monolithic) ----------
__global__ __launch_bounds__(256)
void vq_mono(const float* __restrict__ z,  const float* __restrict__ qw,
             const float* __restrict__ qb, const float* __restrict__ cb,
             const float* __restrict__ pw, const float* __restrict__ pb,
             float* __restrict__ out)
{
    __shared__ float cbn_s[K_];
    __shared__ float lsum[4];
    const int tid = threadIdx.x;
    for (int k = tid; k < K_; k += 256) {
        const float* row = cb + k * D_;
        float s = 0.f;
        #pragma unroll
        for (int d = 0; d < D_; ++d) s = fmaf(row[d], row[d], s);
        cbn_s[k] = s;
    }
    __syncthreads();
    const int token = blockIdx.x * 256 + tid;
    const int b = token >> 12, hw = token & (HW_ - 1);
    const float* zbase = z + (size_t)b * C_ * HW_ + hw;
    float zv[C_];
    #pragma unroll
    for (int c = 0; c < C_; ++c) zv[c] = zbase[(size_t)c * HW_];
    float xf[D_];
    #pragma unroll
    for (int d = 0; d < D_; ++d) {
        float a = qb[d];
        #pragma unroll
        for (int c = 0; c < C_; ++c) a = fmaf(zv[c], qw[d * C_ + c], a);
        xf[d] = a;
    }
    float best = 3.4e38f; int bi = 0;
    #pragma unroll 2
    for (int k = 0; k < K_; ++k) {
        const float* row = cb + k * D_;
        float p0 = 0.f, p1 = 0.f, p2 = 0.f, p3 = 0.f;
        #pragma unroll
        for (int d = 0; d < D_; d += 4) {
            p0 = fmaf(xf[d+0], row[d+0], p0); p1 = fmaf(xf[d+1], row[d+1], p1);
            p2 = fmaf(xf[d+2], row[d+2], p2); p3 = fmaf(xf[d+3], row[d+3], p3);
        }
        const float s = fmaf(-2.f, (p0+p1)+(p2+p3), cbn_s[k]);
        if (s < best) { best = s; bi = k; }
    }
    out[IDX_OFF + token] = (float)bi;
    const float* qrow = cb + (size_t)bi * D_;
    float qv[D_];
    #pragma unroll
    for (int d = 0; d < D_; ++d) qv[d] = qrow[d];
    float l = 0.f;
    #pragma unroll
    for (int d = 0; d < D_; ++d) { const float df = qv[d] - xf[d]; l = fmaf(df, df, l); }
    float* obase = out + (size_t)b * C_ * HW_ + hw;
    #pragma unroll
    for (int c = 0; c < C_; ++c) {
        float a = pb[c];
        #pragma unroll
        for (int d = 0; d < D_; ++d) a = fmaf(qv[d], pw[c * D_ + d], a);
        obase[(size_t)c * HW_] = a;
    }
    #pragma unroll
    for (int off = 32; off; off >>= 1) l += __shfl_down(l, off);
    const int wid = tid >> 6, lane = tid & 63;
    if (lane == 0) lsum[wid] = l;
    __syncthreads();
    if (tid == 0) {
        const float t = (lsum[0] + lsum[1]) + (lsum[2] + lsum[3]);
        atomicAdd(out + LOSS_OFF, t * (2.0f / (float)(NTOK * D_)));
    }
}

extern "C" void kernel_launch(void* const* d_in, const int* in_sizes, int n_in,
                              void* d_out, int out_size, void* d_ws, size_t ws_size,
                              hipStream_t stream) {
    (void)in_sizes; (void)n_in; (void)out_size;
    const float* z  = (const float*)d_in[0];
    const float* qw = (const float*)d_in[1];
    const float* qb = (const float*)d_in[2];
    const float* cb = (const float*)d_in[3];
    const float* pw = (const float*)d_in[4];
    const float* pb = (const float*)d_in[5];
    float* out = (float*)d_out;

    if (ws_size < (size_t)WS_NEEDED) {
        hipMemsetAsync((char*)d_out + (size_t)LOSS_OFF * sizeof(float), 0, sizeof(float), stream);
        vq_mono<<<NTOK / 256, 256, 0, stream>>>(z, qw, qb, cb, pw, pb, out);
        return;
    }
    char* ws = (char*)d_ws;
    float* cbn   = (float*)(ws + WS_CBN);
    short* cbhf  = (short*)(ws + WS_CBHF);
    short* cblf  = (short*)(ws + WS_CBLF);
    float* lossp = (float*)(ws + WS_LOSSP);

    prep_cb<<<2, 256, 0, stream>>>(cb, cbn, cbhf, cblf);
    vq_fused<<<512, 512, 0, stream>>>(z, qw, qb, cb, pw, pb, cbhf, cblf, cbn, lossp, out);
    loss_final<<<1, 256, 0, stream>>>(lossp, out);
}